// Round 14
// baseline (209.208 us; speedup 1.0000x reference)
//
#include <hip/hip_runtime.h>
#include <hip/hip_bf16.h>

// Problem constants
constexpr int kB   = 2;
constexpr int kH   = 8;
constexpr int kG   = 4;
constexpr int kS   = 14;
constexpr int kSS  = 196;   // S*S
constexpr int kKey = 784;   // G*S*S keys per (b,h)
constexpr int kKeyP = 800;  // keys padded to multiple of 32 for MFMA K-loop
constexpr int kMid = 96;
constexpr int kQR  = 28;    // 4 g * 7 j query rows per attention block
constexpr int kPS  = 800;   // contl/P row stride in u16 (R24: 808->800, LDS budget)
constexpr int kXS  = 104;   // Xt/Ws row stride (bf16): 16B-aligned, even b128 bank spread
constexpr float kScl = 0.10206207261596577f; // 1/sqrt(96)
constexpr float kK2  = 0.14724663682f;       // kScl / ln(2)  (exp2 domain)
constexpr float kCc  = 11.5415603272f;       // 8 nats / ln(2): constant softmax shift (exact)

typedef __attribute__((ext_vector_type(8))) short bf16x8;
typedef __attribute__((ext_vector_type(4))) float f32x4;

__device__ __forceinline__ float b2f(short s) {
  return __uint_as_float(((unsigned)(unsigned short)s) << 16);
}

// ---------------- workspace layout (float elements) ----------------
constexpr size_t SZ_QKb = (size_t)kB*kH*kG*kSS*kMid/2; // 602,112 (bf16 in float units)
constexpr size_t OFF_Qb = 0;                            // Qb bf16 [bh][g*196+ij][96]
constexpr size_t OFF_Kb = OFF_Qb + SZ_QKb;              // Kb bf16 [bh][g*196+ij][96]
constexpr size_t OFF_V  = OFF_Kb + SZ_QKb;              // Vb bf16 CHANNEL-MAJOR INTERLEAVED [bh][c][ij*4+g]
constexpr size_t SZ_V   = (size_t)kB*kH*kMid*kKeyP/2;   // 614,400
constexpr size_t OFF_FR = OFF_V + SZ_V;                 // 27*32 row table fp32
constexpr size_t OFF_FC = OFF_FR + 27*32;               // 27*32 col table fp32
constexpr size_t OFF_WOH = OFF_FC + 27*32;              // Woh bf16 [h][d][c] (73,728)

// ============================================================
// Kernel 1 (R21-proven, unchanged): QKV MFMA GEMM, 4x ij-split.
// ============================================================
__global__ __launch_bounds__(512, 8)
void k_qkv(const float* __restrict__ x,
           const float* __restrict__ Wq, const float* __restrict__ bq,
           const float* __restrict__ Wk, const float* __restrict__ bk,
           const float* __restrict__ Wv, const float* __restrict__ bv,
           __hip_bfloat16* __restrict__ Qb, __hip_bfloat16* __restrict__ Kb,
           __hip_bfloat16* __restrict__ Vb,
           const float* __restrict__ rw1, const float* __restrict__ rb1,
           const float* __restrict__ rgam, const float* __restrict__ rbet,
           const float* __restrict__ rw2, const float* __restrict__ rb2,
           const float* __restrict__ cw1, const float* __restrict__ cb1,
           const float* __restrict__ cgam, const float* __restrict__ cbet,
           const float* __restrict__ cw2, const float* __restrict__ cb2,
           float* __restrict__ frow, float* __restrict__ fcol,
           const float* __restrict__ Wo, __hip_bfloat16* __restrict__ Woh,
           float* __restrict__ out0) {
  const int bid = blockIdx.x;          // 0..191: (b, g, mc, nq)
  const int ten = blockIdx.y;
  const int tid = threadIdx.x;
  const int nq = bid % 4;              // ij quarter: 49 ij each
  const int mc = (bid / 4) % 6;        // d-chunk of 128
  const int g  = (bid / 24) % 4;
  const int b  = bid / 96;
  const int d0 = mc * 128;
  const int ij0 = nq * 49;
  const float* W    = (ten == 0) ? Wq : (ten == 1) ? Wk : Wv;
  const float* bias = (ten == 0) ? bq : (ten == 1) ? bk : bv;

  // ---- zero d_out (atomically accumulated by the fused attn kernel)
  {
    int zidx = (ten*192 + bid)*512 + tid;
    if (zidx < 37632) ((float4*)out0)[zidx] = make_float4(0.f, 0.f, 0.f, 0.f);
  }

  __shared__ alignas(16) __hip_bfloat16 Xt[64][kXS];   // x^T bf16, rows >=49 zero
  __shared__ alignas(16) __hip_bfloat16 Ws[128][kXS];  // W chunk bf16

  for (int idx = tid; idx < 24*64; idx += 512) {
    int cq = idx >> 6, r = idx & 63;
    float4 v = make_float4(0.f, 0.f, 0.f, 0.f);
    if (r < 49) {
      const float* xp = x + (((size_t)b*96 + cq*4)*4 + (size_t)g)*196 + ij0 + r;
      v.x = xp[0]; v.y = xp[784]; v.z = xp[1568]; v.w = xp[2352];
    }
    ushort4 u;
    u.x = __bfloat16_as_ushort(__float2bfloat16(v.x));
    u.y = __bfloat16_as_ushort(__float2bfloat16(v.y));
    u.z = __bfloat16_as_ushort(__float2bfloat16(v.z));
    u.w = __bfloat16_as_ushort(__float2bfloat16(v.w));
    *(ushort4*)(&Xt[r][cq*4]) = u;
  }
  for (int idx = tid; idx < 128*24; idx += 512) {
    int dl = idx / 24, cq = idx - dl*24;
    float4 v = *(const float4*)(W + (size_t)(d0 + dl)*96 + cq*4);
    ushort4 u;
    u.x = __bfloat16_as_ushort(__float2bfloat16(v.x));
    u.y = __bfloat16_as_ushort(__float2bfloat16(v.y));
    u.z = __bfloat16_as_ushort(__float2bfloat16(v.z));
    u.w = __bfloat16_as_ushort(__float2bfloat16(v.w));
    *(ushort4*)(&Ws[dl][cq*4]) = u;
  }
  __syncthreads();

  {
    const int lane = tid & 63;
    const int wave = tid >> 6;
    const int col  = lane & 15;
    const int quad = lane >> 4;
    const short* ar = (const short*)(&Ws[wave*16 + col][0]);
    bf16x8 a0 = *(const bf16x8*)(ar + 0*32 + quad*8);
    bf16x8 a1 = *(const bf16x8*)(ar + 1*32 + quad*8);
    bf16x8 a2 = *(const bf16x8*)(ar + 2*32 + quad*8);
    float4 b4 = *(const float4*)(bias + d0 + wave*16 + quad*4);
    float bb[4] = {b4.x, b4.y, b4.z, b4.w};

#pragma unroll
    for (int nt = 0; nt < 4; ++nt) {
      const short* xr = (const short*)(&Xt[nt*16 + col][0]);
      bf16x8 x0 = *(const bf16x8*)(xr + 0*32 + quad*8);
      bf16x8 x1 = *(const bf16x8*)(xr + 1*32 + quad*8);
      bf16x8 x2 = *(const bf16x8*)(xr + 2*32 + quad*8);
      f32x4 acc = {0.f, 0.f, 0.f, 0.f};
      acc = __builtin_amdgcn_mfma_f32_16x16x32_bf16(a0, x0, acc, 0, 0, 0);
      acc = __builtin_amdgcn_mfma_f32_16x16x32_bf16(a1, x1, acc, 0, 0, 0);
      acc = __builtin_amdgcn_mfma_f32_16x16x32_bf16(a2, x2, acc, 0, 0, 0);
      int rl = nt*16 + col;
      if (rl < 49) {
        int ij = ij0 + rl;
#pragma unroll
        for (int r = 0; r < 4; ++r) {
          int d = d0 + wave*16 + quad*4 + r;
          int c = d >> 3, h = d & 7;
          float val = acc[r] + bb[r];
          if (ten == 2) {
            Vb[((size_t)((b*8 + h)*96 + c))*kKeyP + ij*4 + g] = __float2bfloat16(val);
          } else {
            __hip_bfloat16* dst = (ten == 0) ? Qb : Kb;
            dst[((size_t)((b*8 + h)*4 + g)*196 + ij)*96 + c] = __float2bfloat16(val);
          }
        }
      }
    }
  }

  // ---- fused setup tails ----
  if (ten == 1) {
    for (int idx = bid*512 + tid; idx < 73728; idx += 192*512) {
      int h = idx / 9216, rem = idx - h*9216;
      int d = rem / 96, c = rem - d*96;
      Woh[idx] = __float2bfloat16(Wo[(size_t)d*768 + c*8 + h]);
    }
  }
  if (ten == 2 && bid < 16) {
    for (int idx = tid; idx < 96*16; idx += 512) {
      int c = idx >> 4, kp = idx & 15;
      Vb[((size_t)(bid*96 + c))*kKeyP + kKey + kp] = __float2bfloat16(0.f);
    }
  }
  if (ten == 0 && bid == 0 && tid < 54) {
    int t = tid;
    int which = t / 27;
    int n = t % 27;
    float tv = (float)(n - 13) / 13.0f;
    const float* w1  = which ? cw1  : rw1;
    const float* b1  = which ? cb1  : rb1;
    const float* gam = which ? cgam : rgam;
    const float* bet = which ? cbet : rbet;
    const float* w2  = which ? cw2  : rw2;
    const float* b2  = which ? cb2  : rb2;
    float h[16];
    float mu = 0.f;
#pragma unroll
    for (int d = 0; d < 16; ++d) { h[d] = tv * w1[d] + b1[d]; mu += h[d]; }
    mu *= (1.0f/16.0f);
    float var = 0.f;
#pragma unroll
    for (int d = 0; d < 16; ++d) { float z = h[d] - mu; var += z*z; }
    var *= (1.0f/16.0f);
    float rstd = rsqrtf(var + 1e-5f);
#pragma unroll
    for (int d = 0; d < 16; ++d) {
      float z = (h[d] - mu) * rstd * gam[d] + bet[d];
      h[d] = z / (1.0f + expf(-z));   // silu
    }
    float* outp = (which ? fcol : frow) + n*32;
    for (int c = 0; c < 32; ++c) {
      float o = b2[c];
#pragma unroll
      for (int d = 0; d < 16; ++d) o += h[d] * w2[d*32 + c];
      outp[c] = o;
    }
  }
}

// ============================================================
// Kernel 2 (R24): fused attn, LDS cut 79.4 -> 53.3 KB => 3 blocks/CU.
// Cuts vs R21: (a) qs + staged tables deleted -- phase 2b reads Q/tables
// straight from global (all L2-resident; staging them was pure copy);
// kK2 folded once into the final exp2 instead of pre-scaling tables.
// (b) T[4][28][14] deleted -- pass B remapped to tid = q*16+kk (448 = 7
// waves); the 14-wide kk-sum is 4 shfl_xor within each 16-lane group,
// lane kk==0 writes DinvS directly. (c) vos overlays the dead
// ArrE/AclE/AgEall/DinvS pool after pass C. (d) kPS 808->800.
// Barriers 6 -> 4. Numerics identical (sub-ulp reorder from kK2 folding).
// R20 XCD swizzle + R17 in-place P kept.
// ============================================================
__global__ __launch_bounds__(512, 6)
void k_attn(const __hip_bfloat16* __restrict__ Qb, const __hip_bfloat16* __restrict__ Kb,
            const float* __restrict__ frow_g, const float* __restrict__ fcol_g,
            const float* __restrict__ gemb_g,
            const __hip_bfloat16* __restrict__ Vb,
            const __hip_bfloat16* __restrict__ Woh,
            const float* __restrict__ bo, float* __restrict__ out) {
  const int tid = threadIdx.x;
  const int bid = blockIdx.x;
  // ---- XCD-aware decode: bid&7 = XCD slot; 56 blocks/XCD = 2 bh x 28.
  const int xcd  = bid & 7;
  const int slot = bid >> 3;               // 0..55
  const int sub  = (slot >= 28);
  const int within = slot - sub*28;        // 0..27
  const int bh = xcd*2 + sub;
  const int qi = within >> 1;
  const int jhalf = within & 1;

  // ---- LDS: contl 44,800 + pool2 8,512 = 53,312 B ----
  __shared__ alignas(16) __hip_bfloat16 contl[kQR][kPS]; // E -> P in place
  __shared__ alignas(16) char pool2[8512];

  float (*ArrE)[28]    = (float(*)[28])pool2;              // [28][28], 3136 B
  float (*AclE)[28]    = (float(*)[28])(pool2 + 3136);     // [28][28], 3136 B
  float (*AgEall)[kQR][4] = (float(*)[kQR][4])(pool2 + 6272); // [4][28][4], 1792 B
  float* DinvS2        = (float*)(pool2 + 8064);           // [4*28], 448 B
  __hip_bfloat16 (*vos)[104] = (__hip_bfloat16(*)[104])pool2; // [32][104] (phase >=3)

  const short* Qs = (const short*)Qb;
  const short* Ks = (const short*)Kb;

  // ---- zero P pad cols [784,800) (PV reads them; NaN*0=NaN otherwise)
  if (tid < 448) { int r = tid >> 4, kp = tid & 15; contl[r][784 + kp] = __float2bfloat16(0.f); }

  // ---- phase 2a: MFMA content GEMM -> contl (E = exp2(content*kK2 - Cc), bf16)
  {
    const int lane = tid & 63;
    const int wave = tid >> 6;
    const int col  = lane & 15;
    const int quad = lane >> 4;

    bf16x8 afrag[2][3];
#pragma unroll
    for (int mt = 0; mt < 2; ++mt) {
      int m = mt*16 + col;
      int q = (m < kQR) ? m : 0;                 // pad rows: duplicate q0 (discarded)
      const short* qrow = Qs +
          ((size_t)((bh*4 + q/7)*kSS + qi*14 + jhalf*7 + q%7))*96;
#pragma unroll
      for (int ks = 0; ks < 3; ++ks)
        afrag[mt][ks] = *(const bf16x8*)(qrow + ks*32 + quad*8);
    }

    for (int nt = wave; nt < 49; nt += 8) {
      int kl = nt*16 + col;                      // key index g_key*196 + ij
      const short* krow = Ks + ((size_t)(bh*kKey + kl))*96;
      bf16x8 b0 = *(const bf16x8*)(krow + 0*32 + quad*8);
      bf16x8 b1 = *(const bf16x8*)(krow + 1*32 + quad*8);
      bf16x8 b2 = *(const bf16x8*)(krow + 2*32 + quad*8);
      f32x4 c0 = {0.f,0.f,0.f,0.f};
      f32x4 c1 = {0.f,0.f,0.f,0.f};
      c0 = __builtin_amdgcn_mfma_f32_16x16x32_bf16(afrag[0][0], b0, c0, 0, 0, 0);
      c0 = __builtin_amdgcn_mfma_f32_16x16x32_bf16(afrag[0][1], b1, c0, 0, 0, 0);
      c0 = __builtin_amdgcn_mfma_f32_16x16x32_bf16(afrag[0][2], b2, c0, 0, 0, 0);
      c1 = __builtin_amdgcn_mfma_f32_16x16x32_bf16(afrag[1][0], b0, c1, 0, 0, 0);
      c1 = __builtin_amdgcn_mfma_f32_16x16x32_bf16(afrag[1][1], b1, c1, 0, 0, 0);
      c1 = __builtin_amdgcn_mfma_f32_16x16x32_bf16(afrag[1][2], b2, c1, 0, 0, 0);
      int ijn = kl % 196, mk = kl / 196;         // interleaved store position
      // C/D layout: col = lane&15 (=kl), row = quad*4 + r (=q)  [m89]
#pragma unroll
      for (int r = 0; r < 4; ++r) {
        int q0 = quad*4 + r;                     // 0..15, all valid
        contl[q0][ijn*4 + mk] = __float2bfloat16(exp2f(c0[r]*kK2 - kCc));
        int q1 = 16 + quad*4 + r;                // 16..31, valid < 28
        if (q1 < kQR)
          contl[q1][ijn*4 + mk] = __float2bfloat16(exp2f(c1[r]*kK2 - kCc));
      }
    }
  }

  // ---- phase 2b: bias tables from GLOBAL (L2-hot), exp2(acc*kK2) applied.
  {
    auto dot32 = [](const short* qp, const float* tp) -> float {
      float acc = 0.f;
#pragma unroll
      for (int k8 = 0; k8 < 4; ++k8) {
        bf16x8 qv = *(const bf16x8*)(qp + k8*8);
        float4 ta = *(const float4*)(tp + k8*8);
        float4 tb = *(const float4*)(tp + k8*8 + 4);
        acc += b2f(qv[0])*ta.x + b2f(qv[1])*ta.y + b2f(qv[2])*ta.z + b2f(qv[3])*ta.w;
        acc += b2f(qv[4])*tb.x + b2f(qv[5])*tb.y + b2f(qv[6])*tb.z + b2f(qv[7])*tb.w;
      }
      return acc;
    };
    for (int t = tid; t < kQR*58; t += 512) {
      int q = t / 58, s = t - q*58;
      const short* qp = Qs +
          ((size_t)((bh*4 + q/7)*kSS + qi*14 + jhalf*7 + q%7))*96;
      if (s < 27) {
        ArrE[q][s] = exp2f(dot32(qp, frow_g + s*32) * kK2);
      } else if (s < 54) {
        AclE[q][s-27] = exp2f(dot32(qp + 32, fcol_g + (s-27)*32) * kK2);
      } else {
        int p = s - 54;
        float e = exp2f(dot32(qp + 64, gemb_g + p*32) * kK2);
        int gq = q / 7;
        // AgEall[v][q][m] with (m - gq + v)&3 == p  =>  m = (p + gq - v)&3
#pragma unroll
        for (int vv = 0; vv < 4; ++vv)
          AgEall[vv][q][(p + gq - vv + 8) & 3] = e;
      }
    }
  }
  __syncthreads();

  // ---- pass B: tid = q*16 + kk (448 = 7 waves); 16-lane shuffle reduce.
  if (tid < 448) {
    const int qB  = tid >> 4;
    const int kkB = tid & 15;
    float t0 = 0.f, t1 = 0.f, t2 = 0.f, t3 = 0.f;
    if (kkB < 14) {
      const int jlB = jhalf*7 + (qB % 7);
      const int daB = kkB - qi;
      f32x4 ag0 = *(const f32x4*)(&AgEall[0][qB][0]);
      f32x4 ag1 = *(const f32x4*)(&AgEall[1][qB][0]);
      f32x4 ag2 = *(const f32x4*)(&AgEall[2][qB][0]);
      f32x4 ag3 = *(const f32x4*)(&AgEall[3][qB][0]);
      const float* Ar = &ArrE[qB][13];
      const float* Ac = &AclE[qB][13];
      float a0 = 0.f, a1 = 0.f, a2 = 0.f, a3 = 0.f;
#pragma unroll
      for (int ll = 0; ll < 14; ++ll) {
        const int db = ll - jlB;
        ushort4 u = *(const ushort4*)(&contl[qB][(kkB*14 + ll)*4]);
        float e0 = __uint_as_float((unsigned)u.x << 16);
        float e1 = __uint_as_float((unsigned)u.y << 16);
        float e2 = __uint_as_float((unsigned)u.z << 16);
        float e3 = __uint_as_float((unsigned)u.w << 16);
        a0 += Ac[ db] * (e0*ag0.x + e1*ag0.y + e2*ag0.z + e3*ag0.w);
        a1 += Ar[-db] * (e0*ag1.x + e1*ag1.y + e2*ag1.z + e3*ag1.w);
        a2 += Ac[-db] * (e0*ag2.x + e1*ag2.y + e2*ag2.z + e3*ag2.w);
        a3 += Ar[ db] * (e0*ag3.x + e1*ag3.y + e2*ag3.z + e3*ag3.w);
      }
      t0 = Ar[ daB] * a0;
      t1 = Ac[ daB] * a1;
      t2 = Ar[-daB] * a2;
      t3 = Ac[-daB] * a3;
    }
#pragma unroll
    for (int off = 1; off < 16; off <<= 1) {
      t0 += __shfl_xor(t0, off, 16);
      t1 += __shfl_xor(t1, off, 16);
      t2 += __shfl_xor(t2, off, 16);
      t3 += __shfl_xor(t3, off, 16);
    }
    if (kkB == 0) {
      DinvS2[0*28 + qB] = 1.0f / t0;
      DinvS2[1*28 + qB] = 1.0f / t1;
      DinvS2[2*28 + qB] = 1.0f / t2;
      DinvS2[3*28 + qB] = 1.0f / t3;
    }
  }
  __syncthreads();

  const int actv = (tid < 392);
  const int half = actv ? (tid / 196) : 0;
  const int ijC  = actv ? (tid % 196) : 0;
  const int kkC = ijC / 14;
  const int llC = ijC % 14;
  const int daC = kkC - qi;

  // ---- pass C, all 4 v fused, IN PLACE: preload this thread's 28 E words,
  // then overwrite the same cells with P rows [jq*4+v][ij*4+m].
  if (actv) {
    unsigned p32[kQR];
#pragma unroll
    for (int q = 0; q < kQR; ++q)
      p32[q] = *(const unsigned*)(&contl[q][ijC*4 + half*2]);
#pragma unroll
    for (int v = 0; v < 4; ++v) {
      const int s1a = (v==0) ? 1 : (v==2) ? -1 : 0;
      const int s1b = (v==1) ? -1 : (v==3) ? 1 : 0;
      const int s2a = (v==1) ? 1 : (v==3) ? -1 : 0;
      const int s2b = (v==0) ? 1 : (v==2) ? -1 : 0;
#pragma unroll
      for (int jq = 0; jq < 7; ++jq) {
        const int db = llC - (jhalf*7 + jq);
        const int ai = s1a*daC + s1b*db, ci = s2a*daC + s2b*db;
        float am0 = 0.f, am1 = 0.f;
#pragma unroll
        for (int gq = 0; gq < 4; ++gq) {
          const int q = gq*7 + jq;
          const float fq = ArrE[q][13 + ai] * AclE[q][13 + ci] * DinvS2[v*28 + q];
          unsigned u = p32[q];
          float e0 = __uint_as_float(u << 16);
          float e1 = __uint_as_float(u & 0xffff0000u);
          am0 += e0 * (AgEall[v][q][half*2]     * fq);
          am1 += e1 * (AgEall[v][q][half*2 + 1] * fq);
        }
        __hip_bfloat16* pp = &contl[jq*4 + v][ijC*4 + half*2];
        pp[0] = __float2bfloat16(am0);
        pp[1] = __float2bfloat16(am1);
      }
    }
  }
  __syncthreads();   // P complete in contl; ArrE/AclE/AgEall/DinvS dead -> vos

  const int lane = tid & 63;
  const int wave = tid >> 6;
  const int col  = lane & 15;
  const int quad = lane >> 4;
  const int b_ = bh >> 3, h_ = bh & 7;

  // ---- phase 3: PV. vo[28][96] = P[28x800] . V[800x96] (k = ij*4+g order).
  {
    const short* Bp = (const short*)Vb + ((size_t)bh*96)*kKeyP + quad*8;
#pragma unroll
    for (int tk = 0; tk < 2; ++tk) {
      int t = wave + tk*8;
      if (t < 12) {
        int mt = t / 6, nt = t - mt*6;
        int crow = nt*16 + col;
        int prow = mt*16 + col; if (prow >= kQR) prow = 0;  // dup row0 (discarded)
        const short* ap = (const short*)(&contl[prow][0]) + quad*8;
        const short* bp = Bp + (size_t)crow*kKeyP;
        f32x4 acc = {0.f,0.f,0.f,0.f};
        for (int ks = 0; ks < 25; ++ks) {
          bf16x8 a = *(const bf16x8*)(ap + ks*32);
          bf16x8 b = *(const bf16x8*)(bp + ks*32);
          acc = __builtin_amdgcn_mfma_f32_16x16x32_bf16(a, b, acc, 0, 0, 0);
        }
        // D: col = lane&15 (= c in n-tile), row = quad*4 + r (= P row in m-tile)
#pragma unroll
        for (int r = 0; r < 4; ++r)
          vos[mt*16 + quad*4 + r][crow] = __float2bfloat16(acc[r]);
      }
    }
  }
  __syncthreads();

  // ---- phase 4: outproj. out += vos . Woh[h]^T (+ bo if h==0). 12 tasks.
  {
    const short* wb = (const short*)Woh + (size_t)h_*9216;
#pragma unroll
    for (int tk = 0; tk < 2; ++tk) {
      int t = wave + tk*8;
      if (t < 12) {
        int mt = t / 6, dt = t - mt*6;
        f32x4 acc = {0.f,0.f,0.f,0.f};
#pragma unroll
        for (int ks = 0; ks < 3; ++ks) {
          bf16x8 a = *(const bf16x8*)(&vos[mt*16 + col][ks*32 + quad*8]);
          bf16x8 b = *(const bf16x8*)(wb + (size_t)(dt*16 + col)*96 + ks*32 + quad*8);
          acc = __builtin_amdgcn_mfma_f32_16x16x32_bf16(a, b, acc, 0, 0, 0);
        }
        const int d = dt*16 + col;              // D col = lane&15 = d-in-tile
        const float bias = (h_ == 0) ? bo[d] : 0.f;
#pragma unroll
        for (int r = 0; r < 4; ++r) {
          int rr = mt*16 + quad*4 + r;          // P/vo row = jq*4 + v
          if (rr < kQR) {
            int jq = rr >> 2, vv = rr & 3;
            int ijq = qi*14 + jhalf*7 + jq;
            atomicAdd(&out[((size_t)(b_*96 + d)*4 + vv)*kSS + ijq], acc[r] + bias);
          }
        }
      }
    }
  }
}

// ============================================================
extern "C" void kernel_launch(void* const* d_in, const int* in_sizes, int n_in,
                              void* d_out, int out_size, void* d_ws, size_t ws_size,
                              hipStream_t stream) {
  const float* x    = (const float*)d_in[0];
  const float* Wq   = (const float*)d_in[1];
  const float* bq   = (const float*)d_in[2];
  const float* Wk   = (const float*)d_in[3];
  const float* bk   = (const float*)d_in[4];
  const float* Wv   = (const float*)d_in[5];
  const float* bv   = (const float*)d_in[6];
  const float* Wo   = (const float*)d_in[7];
  const float* bo   = (const float*)d_in[8];
  const float* rw1  = (const float*)d_in[9];
  const float* rb1  = (const float*)d_in[10];
  const float* rgam = (const float*)d_in[11];
  const float* rbet = (const float*)d_in[12];
  const float* rw2  = (const float*)d_in[13];
  const float* rb2  = (const float*)d_in[14];
  const float* cw1  = (const float*)d_in[15];
  const float* cb1  = (const float*)d_in[16];
  const float* cgam = (const float*)d_in[17];
  const float* cbet = (const float*)d_in[18];
  const float* cw2  = (const float*)d_in[19];
  const float* cb2  = (const float*)d_in[20];
  const float* gemb = (const float*)d_in[21];
  // d_in[22..24] = row_rel, col_rel, g_idx: reconstructed analytically.

  float* ws = (float*)d_ws;
  __hip_bfloat16* Qb = (__hip_bfloat16*)(ws + OFF_Qb);
  __hip_bfloat16* Kb = (__hip_bfloat16*)(ws + OFF_Kb);
  __hip_bfloat16* Vb = (__hip_bfloat16*)(ws + OFF_V);
  float* Frow = ws + OFF_FR;
  float* Fcol = ws + OFF_FC;
  __hip_bfloat16* Woh = (__hip_bfloat16*)(ws + OFF_WOH);
  float* out  = (float*)d_out;

  k_qkv<<<dim3(192, 3), 512, 0, stream>>>(x, Wq, bq, Wk, bk, Wv, bv, Qb, Kb, Vb,
                                          rw1, rb1, rgam, rbet, rw2, rb2,
                                          cw1, cb1, cgam, cbet, cw2, cb2,
                                          Frow, Fcol, Wo, Woh, out);
  k_attn<<<448, 512, 0, stream>>>(Qb, Kb, Frow, Fcol, gemb, Vb, Woh, bo, out);
}

// Round 15
// 173.273 us; speedup vs baseline: 1.2074x; 1.2074x over previous
//
#include <hip/hip_runtime.h>
#include <hip/hip_bf16.h>

// Problem constants
constexpr int kB   = 2;
constexpr int kH   = 8;
constexpr int kG   = 4;
constexpr int kS   = 14;
constexpr int kSS  = 196;   // S*S
constexpr int kKey = 784;   // G*S*S keys per (b,h)
constexpr int kKeyP = 800;  // keys padded to multiple of 32 for MFMA K-loop
constexpr int kMid = 96;
constexpr int kQR  = 28;    // 4 g * 7 j query rows per attention block
constexpr int kPS  = 800;   // contl/P row stride in u16
constexpr int kXS  = 104;   // Xt/Ws row stride (bf16): 16B-aligned, even b128 bank spread
constexpr float kScl = 0.10206207261596577f; // 1/sqrt(96)
constexpr float kK2  = 0.14724663682f;       // kScl / ln(2)  (exp2 domain)
constexpr float kCc  = 11.5415603272f;       // 8 nats / ln(2): constant softmax shift (exact)

typedef __attribute__((ext_vector_type(8))) short bf16x8;
typedef __attribute__((ext_vector_type(4))) float f32x4;

__device__ __forceinline__ float b2f(short s) {
  return __uint_as_float(((unsigned)(unsigned short)s) << 16);
}

// ---------------- workspace layout (float elements) ----------------
constexpr size_t SZ_QKb = (size_t)kB*kH*kG*kSS*kMid/2; // 602,112 (bf16 in float units)
constexpr size_t OFF_Qb = 0;                            // Qb bf16 [bh][g*196+ij][96]
constexpr size_t OFF_Kb = OFF_Qb + SZ_QKb;              // Kb bf16 [bh][g*196+ij][96]
constexpr size_t OFF_V  = OFF_Kb + SZ_QKb;              // Vb bf16 CHANNEL-MAJOR INTERLEAVED [bh][c][ij*4+g]
constexpr size_t SZ_V   = (size_t)kB*kH*kMid*kKeyP/2;   // 614,400
constexpr size_t OFF_FR = OFF_V + SZ_V;                 // 27*32 row table fp32
constexpr size_t OFF_FC = OFF_FR + 27*32;               // 27*32 col table fp32
constexpr size_t OFF_WOH = OFF_FC + 27*32;              // Woh bf16 [h][d][c] (73,728)

// ============================================================
// Kernel 1 (R21-proven, unchanged): QKV MFMA GEMM, 4x ij-split.
// ============================================================
__global__ __launch_bounds__(512, 8)
void k_qkv(const float* __restrict__ x,
           const float* __restrict__ Wq, const float* __restrict__ bq,
           const float* __restrict__ Wk, const float* __restrict__ bk,
           const float* __restrict__ Wv, const float* __restrict__ bv,
           __hip_bfloat16* __restrict__ Qb, __hip_bfloat16* __restrict__ Kb,
           __hip_bfloat16* __restrict__ Vb,
           const float* __restrict__ rw1, const float* __restrict__ rb1,
           const float* __restrict__ rgam, const float* __restrict__ rbet,
           const float* __restrict__ rw2, const float* __restrict__ rb2,
           const float* __restrict__ cw1, const float* __restrict__ cb1,
           const float* __restrict__ cgam, const float* __restrict__ cbet,
           const float* __restrict__ cw2, const float* __restrict__ cb2,
           float* __restrict__ frow, float* __restrict__ fcol,
           const float* __restrict__ Wo, __hip_bfloat16* __restrict__ Woh,
           float* __restrict__ out0) {
  const int bid = blockIdx.x;          // 0..191: (b, g, mc, nq)
  const int ten = blockIdx.y;
  const int tid = threadIdx.x;
  const int nq = bid % 4;              // ij quarter: 49 ij each
  const int mc = (bid / 4) % 6;        // d-chunk of 128
  const int g  = (bid / 24) % 4;
  const int b  = bid / 96;
  const int d0 = mc * 128;
  const int ij0 = nq * 49;
  const float* W    = (ten == 0) ? Wq : (ten == 1) ? Wk : Wv;
  const float* bias = (ten == 0) ? bq : (ten == 1) ? bk : bv;

  // ---- zero d_out (atomically accumulated by the fused attn kernel)
  {
    int zidx = (ten*192 + bid)*512 + tid;
    if (zidx < 37632) ((float4*)out0)[zidx] = make_float4(0.f, 0.f, 0.f, 0.f);
  }

  __shared__ alignas(16) __hip_bfloat16 Xt[64][kXS];   // x^T bf16, rows >=49 zero
  __shared__ alignas(16) __hip_bfloat16 Ws[128][kXS];  // W chunk bf16

  for (int idx = tid; idx < 24*64; idx += 512) {
    int cq = idx >> 6, r = idx & 63;
    float4 v = make_float4(0.f, 0.f, 0.f, 0.f);
    if (r < 49) {
      const float* xp = x + (((size_t)b*96 + cq*4)*4 + (size_t)g)*196 + ij0 + r;
      v.x = xp[0]; v.y = xp[784]; v.z = xp[1568]; v.w = xp[2352];
    }
    ushort4 u;
    u.x = __bfloat16_as_ushort(__float2bfloat16(v.x));
    u.y = __bfloat16_as_ushort(__float2bfloat16(v.y));
    u.z = __bfloat16_as_ushort(__float2bfloat16(v.z));
    u.w = __bfloat16_as_ushort(__float2bfloat16(v.w));
    *(ushort4*)(&Xt[r][cq*4]) = u;
  }
  for (int idx = tid; idx < 128*24; idx += 512) {
    int dl = idx / 24, cq = idx - dl*24;
    float4 v = *(const float4*)(W + (size_t)(d0 + dl)*96 + cq*4);
    ushort4 u;
    u.x = __bfloat16_as_ushort(__float2bfloat16(v.x));
    u.y = __bfloat16_as_ushort(__float2bfloat16(v.y));
    u.z = __bfloat16_as_ushort(__float2bfloat16(v.z));
    u.w = __bfloat16_as_ushort(__float2bfloat16(v.w));
    *(ushort4*)(&Ws[dl][cq*4]) = u;
  }
  __syncthreads();

  {
    const int lane = tid & 63;
    const int wave = tid >> 6;
    const int col  = lane & 15;
    const int quad = lane >> 4;
    const short* ar = (const short*)(&Ws[wave*16 + col][0]);
    bf16x8 a0 = *(const bf16x8*)(ar + 0*32 + quad*8);
    bf16x8 a1 = *(const bf16x8*)(ar + 1*32 + quad*8);
    bf16x8 a2 = *(const bf16x8*)(ar + 2*32 + quad*8);
    float4 b4 = *(const float4*)(bias + d0 + wave*16 + quad*4);
    float bb[4] = {b4.x, b4.y, b4.z, b4.w};

#pragma unroll
    for (int nt = 0; nt < 4; ++nt) {
      const short* xr = (const short*)(&Xt[nt*16 + col][0]);
      bf16x8 x0 = *(const bf16x8*)(xr + 0*32 + quad*8);
      bf16x8 x1 = *(const bf16x8*)(xr + 1*32 + quad*8);
      bf16x8 x2 = *(const bf16x8*)(xr + 2*32 + quad*8);
      f32x4 acc = {0.f, 0.f, 0.f, 0.f};
      acc = __builtin_amdgcn_mfma_f32_16x16x32_bf16(a0, x0, acc, 0, 0, 0);
      acc = __builtin_amdgcn_mfma_f32_16x16x32_bf16(a1, x1, acc, 0, 0, 0);
      acc = __builtin_amdgcn_mfma_f32_16x16x32_bf16(a2, x2, acc, 0, 0, 0);
      int rl = nt*16 + col;
      if (rl < 49) {
        int ij = ij0 + rl;
#pragma unroll
        for (int r = 0; r < 4; ++r) {
          int d = d0 + wave*16 + quad*4 + r;
          int c = d >> 3, h = d & 7;
          float val = acc[r] + bb[r];
          if (ten == 2) {
            Vb[((size_t)((b*8 + h)*96 + c))*kKeyP + ij*4 + g] = __float2bfloat16(val);
          } else {
            __hip_bfloat16* dst = (ten == 0) ? Qb : Kb;
            dst[((size_t)((b*8 + h)*4 + g)*196 + ij)*96 + c] = __float2bfloat16(val);
          }
        }
      }
    }
  }

  // ---- fused setup tails ----
  if (ten == 1) {
    for (int idx = bid*512 + tid; idx < 73728; idx += 192*512) {
      int h = idx / 9216, rem = idx - h*9216;
      int d = rem / 96, c = rem - d*96;
      Woh[idx] = __float2bfloat16(Wo[(size_t)d*768 + c*8 + h]);
    }
  }
  if (ten == 2 && bid < 16) {
    for (int idx = tid; idx < 96*16; idx += 512) {
      int c = idx >> 4, kp = idx & 15;
      Vb[((size_t)(bid*96 + c))*kKeyP + kKey + kp] = __float2bfloat16(0.f);
    }
  }
  if (ten == 0 && bid == 0 && tid < 54) {
    int t = tid;
    int which = t / 27;
    int n = t % 27;
    float tv = (float)(n - 13) / 13.0f;
    const float* w1  = which ? cw1  : rw1;
    const float* b1  = which ? cb1  : rb1;
    const float* gam = which ? cgam : rgam;
    const float* bet = which ? cbet : rbet;
    const float* w2  = which ? cw2  : rw2;
    const float* b2  = which ? cb2  : rb2;
    float h[16];
    float mu = 0.f;
#pragma unroll
    for (int d = 0; d < 16; ++d) { h[d] = tv * w1[d] + b1[d]; mu += h[d]; }
    mu *= (1.0f/16.0f);
    float var = 0.f;
#pragma unroll
    for (int d = 0; d < 16; ++d) { float z = h[d] - mu; var += z*z; }
    var *= (1.0f/16.0f);
    float rstd = rsqrtf(var + 1e-5f);
#pragma unroll
    for (int d = 0; d < 16; ++d) {
      float z = (h[d] - mu) * rstd * gam[d] + bet[d];
      h[d] = z / (1.0f + expf(-z));   // silu
    }
    float* outp = (which ? fcol : frow) + n*32;
    for (int c = 0; c < 32; ++c) {
      float o = b2[c];
#pragma unroll
      for (int d = 0; d < 16; ++d) o += h[d] * w2[d*32 + c];
      outp[c] = o;
    }
  }
}

// ============================================================
// Kernel 2 (R25): R24's LDS-cut structure (53.3KB -> 3 blocks/CU by LDS)
// with __launch_bounds__(512,4). R24's (512,6) capped VGPR at ~85-with-
// granularity and spilled pass C's p32[28] to scratch (VGPR 40, WRITE
// 69MB, 96us). The (512,4) cap (128) removes the spill; runtime occupancy
// reaches 3 blocks/CU iff the allocator lands <=85 VGPR (R21 build: 56).
// Structure: no qs/table staging (global reads, L2-hot); pass B remapped
// to tid=q*16+kk with 16-lane shuffle reduce (T[] deleted); vos overlays
// dead tables after pass C; kPS=800. XCD swizzle + in-place P kept.
// ============================================================
__global__ __launch_bounds__(512, 4)
void k_attn(const __hip_bfloat16* __restrict__ Qb, const __hip_bfloat16* __restrict__ Kb,
            const float* __restrict__ frow_g, const float* __restrict__ fcol_g,
            const float* __restrict__ gemb_g,
            const __hip_bfloat16* __restrict__ Vb,
            const __hip_bfloat16* __restrict__ Woh,
            const float* __restrict__ bo, float* __restrict__ out) {
  const int tid = threadIdx.x;
  const int bid = blockIdx.x;
  // ---- XCD-aware decode: bid&7 = XCD slot; 56 blocks/XCD = 2 bh x 28.
  const int xcd  = bid & 7;
  const int slot = bid >> 3;               // 0..55
  const int sub  = (slot >= 28);
  const int within = slot - sub*28;        // 0..27
  const int bh = xcd*2 + sub;
  const int qi = within >> 1;
  const int jhalf = within & 1;

  // ---- LDS: contl 44,800 + pool2 8,512 = 53,312 B ----
  __shared__ alignas(16) __hip_bfloat16 contl[kQR][kPS]; // E -> P in place
  __shared__ alignas(16) char pool2[8512];

  float (*ArrE)[28]    = (float(*)[28])pool2;              // [28][28], 3136 B
  float (*AclE)[28]    = (float(*)[28])(pool2 + 3136);     // [28][28], 3136 B
  float (*AgEall)[kQR][4] = (float(*)[kQR][4])(pool2 + 6272); // [4][28][4], 1792 B
  float* DinvS2        = (float*)(pool2 + 8064);           // [4*28], 448 B
  __hip_bfloat16 (*vos)[104] = (__hip_bfloat16(*)[104])pool2; // [32][104] (phase >=3)

  const short* Qs = (const short*)Qb;
  const short* Ks = (const short*)Kb;

  // ---- zero P pad cols [784,800) (PV reads them; NaN*0=NaN otherwise)
  if (tid < 448) { int r = tid >> 4, kp = tid & 15; contl[r][784 + kp] = __float2bfloat16(0.f); }

  // ---- phase 2a: MFMA content GEMM -> contl (E = exp2(content*kK2 - Cc), bf16)
  {
    const int lane = tid & 63;
    const int wave = tid >> 6;
    const int col  = lane & 15;
    const int quad = lane >> 4;

    bf16x8 afrag[2][3];
#pragma unroll
    for (int mt = 0; mt < 2; ++mt) {
      int m = mt*16 + col;
      int q = (m < kQR) ? m : 0;                 // pad rows: duplicate q0 (discarded)
      const short* qrow = Qs +
          ((size_t)((bh*4 + q/7)*kSS + qi*14 + jhalf*7 + q%7))*96;
#pragma unroll
      for (int ks = 0; ks < 3; ++ks)
        afrag[mt][ks] = *(const bf16x8*)(qrow + ks*32 + quad*8);
    }

    for (int nt = wave; nt < 49; nt += 8) {
      int kl = nt*16 + col;                      // key index g_key*196 + ij
      const short* krow = Ks + ((size_t)(bh*kKey + kl))*96;
      bf16x8 b0 = *(const bf16x8*)(krow + 0*32 + quad*8);
      bf16x8 b1 = *(const bf16x8*)(krow + 1*32 + quad*8);
      bf16x8 b2 = *(const bf16x8*)(krow + 2*32 + quad*8);
      f32x4 c0 = {0.f,0.f,0.f,0.f};
      f32x4 c1 = {0.f,0.f,0.f,0.f};
      c0 = __builtin_amdgcn_mfma_f32_16x16x32_bf16(afrag[0][0], b0, c0, 0, 0, 0);
      c0 = __builtin_amdgcn_mfma_f32_16x16x32_bf16(afrag[0][1], b1, c0, 0, 0, 0);
      c0 = __builtin_amdgcn_mfma_f32_16x16x32_bf16(afrag[0][2], b2, c0, 0, 0, 0);
      c1 = __builtin_amdgcn_mfma_f32_16x16x32_bf16(afrag[1][0], b0, c1, 0, 0, 0);
      c1 = __builtin_amdgcn_mfma_f32_16x16x32_bf16(afrag[1][1], b1, c1, 0, 0, 0);
      c1 = __builtin_amdgcn_mfma_f32_16x16x32_bf16(afrag[1][2], b2, c1, 0, 0, 0);
      int ijn = kl % 196, mk = kl / 196;         // interleaved store position
      // C/D layout: col = lane&15 (=kl), row = quad*4 + r (=q)  [m89]
#pragma unroll
      for (int r = 0; r < 4; ++r) {
        int q0 = quad*4 + r;                     // 0..15, all valid
        contl[q0][ijn*4 + mk] = __float2bfloat16(exp2f(c0[r]*kK2 - kCc));
        int q1 = 16 + quad*4 + r;                // 16..31, valid < 28
        if (q1 < kQR)
          contl[q1][ijn*4 + mk] = __float2bfloat16(exp2f(c1[r]*kK2 - kCc));
      }
    }
  }

  // ---- phase 2b: bias tables from GLOBAL (L2-hot), exp2(acc*kK2) applied.
  {
    auto dot32 = [](const short* qp, const float* tp) -> float {
      float acc = 0.f;
#pragma unroll
      for (int k8 = 0; k8 < 4; ++k8) {
        bf16x8 qv = *(const bf16x8*)(qp + k8*8);
        float4 ta = *(const float4*)(tp + k8*8);
        float4 tb = *(const float4*)(tp + k8*8 + 4);
        acc += b2f(qv[0])*ta.x + b2f(qv[1])*ta.y + b2f(qv[2])*ta.z + b2f(qv[3])*ta.w;
        acc += b2f(qv[4])*tb.x + b2f(qv[5])*tb.y + b2f(qv[6])*tb.z + b2f(qv[7])*tb.w;
      }
      return acc;
    };
    for (int t = tid; t < kQR*58; t += 512) {
      int q = t / 58, s = t - q*58;
      const short* qp = Qs +
          ((size_t)((bh*4 + q/7)*kSS + qi*14 + jhalf*7 + q%7))*96;
      if (s < 27) {
        ArrE[q][s] = exp2f(dot32(qp, frow_g + s*32) * kK2);
      } else if (s < 54) {
        AclE[q][s-27] = exp2f(dot32(qp + 32, fcol_g + (s-27)*32) * kK2);
      } else {
        int p = s - 54;
        float e = exp2f(dot32(qp + 64, gemb_g + p*32) * kK2);
        int gq = q / 7;
        // AgEall[v][q][m] with (m - gq + v)&3 == p  =>  m = (p + gq - v)&3
#pragma unroll
        for (int vv = 0; vv < 4; ++vv)
          AgEall[vv][q][(p + gq - vv + 8) & 3] = e;
      }
    }
  }
  __syncthreads();

  // ---- pass B: tid = q*16 + kk (448 = 7 waves); 16-lane shuffle reduce.
  if (tid < 448) {
    const int qB  = tid >> 4;
    const int kkB = tid & 15;
    float t0 = 0.f, t1 = 0.f, t2 = 0.f, t3 = 0.f;
    if (kkB < 14) {
      const int jlB = jhalf*7 + (qB % 7);
      const int daB = kkB - qi;
      f32x4 ag0 = *(const f32x4*)(&AgEall[0][qB][0]);
      f32x4 ag1 = *(const f32x4*)(&AgEall[1][qB][0]);
      f32x4 ag2 = *(const f32x4*)(&AgEall[2][qB][0]);
      f32x4 ag3 = *(const f32x4*)(&AgEall[3][qB][0]);
      const float* Ar = &ArrE[qB][13];
      const float* Ac = &AclE[qB][13];
      float a0 = 0.f, a1 = 0.f, a2 = 0.f, a3 = 0.f;
#pragma unroll
      for (int ll = 0; ll < 14; ++ll) {
        const int db = ll - jlB;
        ushort4 u = *(const ushort4*)(&contl[qB][(kkB*14 + ll)*4]);
        float e0 = __uint_as_float((unsigned)u.x << 16);
        float e1 = __uint_as_float((unsigned)u.y << 16);
        float e2 = __uint_as_float((unsigned)u.z << 16);
        float e3 = __uint_as_float((unsigned)u.w << 16);
        a0 += Ac[ db] * (e0*ag0.x + e1*ag0.y + e2*ag0.z + e3*ag0.w);
        a1 += Ar[-db] * (e0*ag1.x + e1*ag1.y + e2*ag1.z + e3*ag1.w);
        a2 += Ac[-db] * (e0*ag2.x + e1*ag2.y + e2*ag2.z + e3*ag2.w);
        a3 += Ar[ db] * (e0*ag3.x + e1*ag3.y + e2*ag3.z + e3*ag3.w);
      }
      t0 = Ar[ daB] * a0;
      t1 = Ac[ daB] * a1;
      t2 = Ar[-daB] * a2;
      t3 = Ac[-daB] * a3;
    }
#pragma unroll
    for (int off = 1; off < 16; off <<= 1) {
      t0 += __shfl_xor(t0, off, 16);
      t1 += __shfl_xor(t1, off, 16);
      t2 += __shfl_xor(t2, off, 16);
      t3 += __shfl_xor(t3, off, 16);
    }
    if (kkB == 0) {
      DinvS2[0*28 + qB] = 1.0f / t0;
      DinvS2[1*28 + qB] = 1.0f / t1;
      DinvS2[2*28 + qB] = 1.0f / t2;
      DinvS2[3*28 + qB] = 1.0f / t3;
    }
  }
  __syncthreads();

  const int actv = (tid < 392);
  const int half = actv ? (tid / 196) : 0;
  const int ijC  = actv ? (tid % 196) : 0;
  const int kkC = ijC / 14;
  const int llC = ijC % 14;
  const int daC = kkC - qi;

  // ---- pass C, all 4 v fused, IN PLACE: preload this thread's 28 E words,
  // then overwrite the same cells with P rows [jq*4+v][ij*4+m].
  if (actv) {
    unsigned p32[kQR];
#pragma unroll
    for (int q = 0; q < kQR; ++q)
      p32[q] = *(const unsigned*)(&contl[q][ijC*4 + half*2]);
#pragma unroll
    for (int v = 0; v < 4; ++v) {
      const int s1a = (v==0) ? 1 : (v==2) ? -1 : 0;
      const int s1b = (v==1) ? -1 : (v==3) ? 1 : 0;
      const int s2a = (v==1) ? 1 : (v==3) ? -1 : 0;
      const int s2b = (v==0) ? 1 : (v==2) ? -1 : 0;
#pragma unroll
      for (int jq = 0; jq < 7; ++jq) {
        const int db = llC - (jhalf*7 + jq);
        const int ai = s1a*daC + s1b*db, ci = s2a*daC + s2b*db;
        float am0 = 0.f, am1 = 0.f;
#pragma unroll
        for (int gq = 0; gq < 4; ++gq) {
          const int q = gq*7 + jq;
          const float fq = ArrE[q][13 + ai] * AclE[q][13 + ci] * DinvS2[v*28 + q];
          unsigned u = p32[q];
          float e0 = __uint_as_float(u << 16);
          float e1 = __uint_as_float(u & 0xffff0000u);
          am0 += e0 * (AgEall[v][q][half*2]     * fq);
          am1 += e1 * (AgEall[v][q][half*2 + 1] * fq);
        }
        __hip_bfloat16* pp = &contl[jq*4 + v][ijC*4 + half*2];
        pp[0] = __float2bfloat16(am0);
        pp[1] = __float2bfloat16(am1);
      }
    }
  }
  __syncthreads();   // P complete in contl; ArrE/AclE/AgEall/DinvS dead -> vos

  const int lane = tid & 63;
  const int wave = tid >> 6;
  const int col  = lane & 15;
  const int quad = lane >> 4;
  const int b_ = bh >> 3, h_ = bh & 7;

  // ---- phase 3: PV. vo[28][96] = P[28x800] . V[800x96] (k = ij*4+g order).
  {
    const short* Bp = (const short*)Vb + ((size_t)bh*96)*kKeyP + quad*8;
#pragma unroll
    for (int tk = 0; tk < 2; ++tk) {
      int t = wave + tk*8;
      if (t < 12) {
        int mt = t / 6, nt = t - mt*6;
        int crow = nt*16 + col;
        int prow = mt*16 + col; if (prow >= kQR) prow = 0;  // dup row0 (discarded)
        const short* ap = (const short*)(&contl[prow][0]) + quad*8;
        const short* bp = Bp + (size_t)crow*kKeyP;
        f32x4 acc = {0.f,0.f,0.f,0.f};
        for (int ks = 0; ks < 25; ++ks) {
          bf16x8 a = *(const bf16x8*)(ap + ks*32);
          bf16x8 b = *(const bf16x8*)(bp + ks*32);
          acc = __builtin_amdgcn_mfma_f32_16x16x32_bf16(a, b, acc, 0, 0, 0);
        }
        // D: col = lane&15 (= c in n-tile), row = quad*4 + r (= P row in m-tile)
#pragma unroll
        for (int r = 0; r < 4; ++r)
          vos[mt*16 + quad*4 + r][crow] = __float2bfloat16(acc[r]);
      }
    }
  }
  __syncthreads();

  // ---- phase 4: outproj. out += vos . Woh[h]^T (+ bo if h==0). 12 tasks.
  {
    const short* wb = (const short*)Woh + (size_t)h_*9216;
#pragma unroll
    for (int tk = 0; tk < 2; ++tk) {
      int t = wave + tk*8;
      if (t < 12) {
        int mt = t / 6, dt = t - mt*6;
        f32x4 acc = {0.f,0.f,0.f,0.f};
#pragma unroll
        for (int ks = 0; ks < 3; ++ks) {
          bf16x8 a = *(const bf16x8*)(&vos[mt*16 + col][ks*32 + quad*8]);
          bf16x8 b = *(const bf16x8*)(wb + (size_t)(dt*16 + col)*96 + ks*32 + quad*8);
          acc = __builtin_amdgcn_mfma_f32_16x16x32_bf16(a, b, acc, 0, 0, 0);
        }
        const int d = dt*16 + col;              // D col = lane&15 = d-in-tile
        const float bias = (h_ == 0) ? bo[d] : 0.f;
#pragma unroll
        for (int r = 0; r < 4; ++r) {
          int rr = mt*16 + quad*4 + r;          // P/vo row = jq*4 + v
          if (rr < kQR) {
            int jq = rr >> 2, vv = rr & 3;
            int ijq = qi*14 + jhalf*7 + jq;
            atomicAdd(&out[((size_t)(b_*96 + d)*4 + vv)*kSS + ijq], acc[r] + bias);
          }
        }
      }
    }
  }
}

// ============================================================
extern "C" void kernel_launch(void* const* d_in, const int* in_sizes, int n_in,
                              void* d_out, int out_size, void* d_ws, size_t ws_size,
                              hipStream_t stream) {
  const float* x    = (const float*)d_in[0];
  const float* Wq   = (const float*)d_in[1];
  const float* bq   = (const float*)d_in[2];
  const float* Wk   = (const float*)d_in[3];
  const float* bk   = (const float*)d_in[4];
  const float* Wv   = (const float*)d_in[5];
  const float* bv   = (const float*)d_in[6];
  const float* Wo   = (const float*)d_in[7];
  const float* bo   = (const float*)d_in[8];
  const float* rw1  = (const float*)d_in[9];
  const float* rb1  = (const float*)d_in[10];
  const float* rgam = (const float*)d_in[11];
  const float* rbet = (const float*)d_in[12];
  const float* rw2  = (const float*)d_in[13];
  const float* rb2  = (const float*)d_in[14];
  const float* cw1  = (const float*)d_in[15];
  const float* cb1  = (const float*)d_in[16];
  const float* cgam = (const float*)d_in[17];
  const float* cbet = (const float*)d_in[18];
  const float* cw2  = (const float*)d_in[19];
  const float* cb2  = (const float*)d_in[20];
  const float* gemb = (const float*)d_in[21];
  // d_in[22..24] = row_rel, col_rel, g_idx: reconstructed analytically.

  float* ws = (float*)d_ws;
  __hip_bfloat16* Qb = (__hip_bfloat16*)(ws + OFF_Qb);
  __hip_bfloat16* Kb = (__hip_bfloat16*)(ws + OFF_Kb);
  __hip_bfloat16* Vb = (__hip_bfloat16*)(ws + OFF_V);
  float* Frow = ws + OFF_FR;
  float* Fcol = ws + OFF_FC;
  __hip_bfloat16* Woh = (__hip_bfloat16*)(ws + OFF_WOH);
  float* out  = (float*)d_out;

  k_qkv<<<dim3(192, 3), 512, 0, stream>>>(x, Wq, bq, Wk, bk, Wv, bv, Qb, Kb, Vb,
                                          rw1, rb1, rgam, rbet, rw2, rb2,
                                          cw1, cb1, cgam, cbet, cw2, cb2,
                                          Frow, Fcol, Wo, Woh, out);
  k_attn<<<448, 512, 0, stream>>>(Qb, Kb, Frow, Fcol, gemb, Vb, Woh, bo, out);
}

// Round 16
// 161.811 us; speedup vs baseline: 1.2929x; 1.0708x over previous
//
#include <hip/hip_runtime.h>
#include <hip/hip_bf16.h>

// Problem constants
constexpr int kB   = 2;
constexpr int kH   = 8;
constexpr int kG   = 4;
constexpr int kS   = 14;
constexpr int kSS  = 196;   // S*S
constexpr int kKey = 784;   // G*S*S keys per (b,h)
constexpr int kKeyP = 800;  // keys padded to multiple of 32 for MFMA K-loop
constexpr int kMid = 96;
constexpr int kQR  = 28;    // 4 g * 7 j query rows per attention block
constexpr int kPS  = 808;   // contl/P row stride in u16 (E and P, interleaved k = ij*4+m)
constexpr int kTS  = 36;    // bias-table row stride (fp32): 16B-aligned, banks rotate 4/row
constexpr int kXS  = 104;   // Xt/Ws row stride (bf16): 16B-aligned, even b128 bank spread
constexpr float kScl = 0.10206207261596577f; // 1/sqrt(96)
constexpr float kK2  = 0.14724663682f;       // kScl / ln(2)  (exp2 domain)
constexpr float kCc  = 11.5415603272f;       // 8 nats / ln(2): constant softmax shift (exact)

typedef __attribute__((ext_vector_type(8))) short bf16x8;
typedef __attribute__((ext_vector_type(4))) float f32x4;

// ---------------- workspace layout (float elements) ----------------
constexpr size_t SZ_QKb = (size_t)kB*kH*kG*kSS*kMid/2; // 602,112 (bf16 in float units)
constexpr size_t OFF_Qb = 0;                            // Qb bf16 [bh][g*196+ij][96]
constexpr size_t OFF_Kb = OFF_Qb + SZ_QKb;              // Kb bf16 [bh][g*196+ij][96]
constexpr size_t OFF_V  = OFF_Kb + SZ_QKb;              // Vb bf16 CHANNEL-MAJOR INTERLEAVED [bh][c][ij*4+g]
constexpr size_t SZ_V   = (size_t)kB*kH*kMid*kKeyP/2;   // 614,400
constexpr size_t OFF_FR = OFF_V + SZ_V;                 // 27*32 row table fp32
constexpr size_t OFF_FC = OFF_FR + 27*32;               // 27*32 col table fp32
constexpr size_t OFF_WOH = OFF_FC + 27*32;              // Woh bf16 [h][d][c] (73,728)

// ============================================================
// Kernel 1 (R21-proven): QKV MFMA GEMM, grid split 4x along ij.
// Each block: 128 d x 49 ij (quarter nq); grid (192,3) = 576 blocks.
// Coalesced staged operands; wave = m-tile; V stored k-INTERLEAVED
// [bh][c][ij*4+g] (R17, for in-place P in k_attn).
// ============================================================
__global__ __launch_bounds__(512, 8)
void k_qkv(const float* __restrict__ x,
           const float* __restrict__ Wq, const float* __restrict__ bq,
           const float* __restrict__ Wk, const float* __restrict__ bk,
           const float* __restrict__ Wv, const float* __restrict__ bv,
           __hip_bfloat16* __restrict__ Qb, __hip_bfloat16* __restrict__ Kb,
           __hip_bfloat16* __restrict__ Vb,
           const float* __restrict__ rw1, const float* __restrict__ rb1,
           const float* __restrict__ rgam, const float* __restrict__ rbet,
           const float* __restrict__ rw2, const float* __restrict__ rb2,
           const float* __restrict__ cw1, const float* __restrict__ cb1,
           const float* __restrict__ cgam, const float* __restrict__ cbet,
           const float* __restrict__ cw2, const float* __restrict__ cb2,
           float* __restrict__ frow, float* __restrict__ fcol,
           const float* __restrict__ Wo, __hip_bfloat16* __restrict__ Woh,
           float* __restrict__ out0) {
  const int bid = blockIdx.x;          // 0..191: (b, g, mc, nq)
  const int ten = blockIdx.y;
  const int tid = threadIdx.x;
  const int nq = bid % 4;              // ij quarter: 49 ij each
  const int mc = (bid / 4) % 6;        // d-chunk of 128
  const int g  = (bid / 24) % 4;
  const int b  = bid / 96;
  const int d0 = mc * 128;
  const int ij0 = nq * 49;
  const float* W    = (ten == 0) ? Wq : (ten == 1) ? Wk : Wv;
  const float* bias = (ten == 0) ? bq : (ten == 1) ? bk : bv;

  // ---- zero d_out (atomically accumulated by the fused attn kernel)
  {
    int zidx = (ten*192 + bid)*512 + tid;         // covers 0..294911 >= 37632
    if (zidx < 37632) ((float4*)out0)[zidx] = make_float4(0.f, 0.f, 0.f, 0.f);
  }

  __shared__ alignas(16) __hip_bfloat16 Xt[64][kXS];   // x^T bf16, rows >=49 zero
  __shared__ alignas(16) __hip_bfloat16 Ws[128][kXS];  // W chunk bf16

  // ---- stage Xt: idx = cq*64 + r; coalesced x reads (consecutive ij)
  for (int idx = tid; idx < 24*64; idx += 512) {
    int cq = idx >> 6, r = idx & 63;
    float4 v = make_float4(0.f, 0.f, 0.f, 0.f);
    if (r < 49) {
      const float* xp = x + (((size_t)b*96 + cq*4)*4 + (size_t)g)*196 + ij0 + r;
      v.x = xp[0]; v.y = xp[784]; v.z = xp[1568]; v.w = xp[2352];
    }
    ushort4 u;
    u.x = __bfloat16_as_ushort(__float2bfloat16(v.x));
    u.y = __bfloat16_as_ushort(__float2bfloat16(v.y));
    u.z = __bfloat16_as_ushort(__float2bfloat16(v.z));
    u.w = __bfloat16_as_ushort(__float2bfloat16(v.w));
    *(ushort4*)(&Xt[r][cq*4]) = u;
  }
  // ---- stage Ws: idx = dl*24 + cq; fully coalesced W reads (linear)
  for (int idx = tid; idx < 128*24; idx += 512) {
    int dl = idx / 24, cq = idx - dl*24;
    float4 v = *(const float4*)(W + (size_t)(d0 + dl)*96 + cq*4);
    ushort4 u;
    u.x = __bfloat16_as_ushort(__float2bfloat16(v.x));
    u.y = __bfloat16_as_ushort(__float2bfloat16(v.y));
    u.z = __bfloat16_as_ushort(__float2bfloat16(v.z));
    u.w = __bfloat16_as_ushort(__float2bfloat16(v.w));
    *(ushort4*)(&Ws[dl][cq*4]) = u;
  }
  __syncthreads();

  // ---- MFMA: wave = m-tile (16 d), 4 n-tiles of 16 ij (49 valid), K = 3x32.
  {
    const int lane = tid & 63;
    const int wave = tid >> 6;
    const int col  = lane & 15;
    const int quad = lane >> 4;
    const short* ar = (const short*)(&Ws[wave*16 + col][0]);
    bf16x8 a0 = *(const bf16x8*)(ar + 0*32 + quad*8);
    bf16x8 a1 = *(const bf16x8*)(ar + 1*32 + quad*8);
    bf16x8 a2 = *(const bf16x8*)(ar + 2*32 + quad*8);
    float4 b4 = *(const float4*)(bias + d0 + wave*16 + quad*4);
    float bb[4] = {b4.x, b4.y, b4.z, b4.w};

#pragma unroll
    for (int nt = 0; nt < 4; ++nt) {
      const short* xr = (const short*)(&Xt[nt*16 + col][0]);
      bf16x8 x0 = *(const bf16x8*)(xr + 0*32 + quad*8);
      bf16x8 x1 = *(const bf16x8*)(xr + 1*32 + quad*8);
      bf16x8 x2 = *(const bf16x8*)(xr + 2*32 + quad*8);
      f32x4 acc = {0.f, 0.f, 0.f, 0.f};
      acc = __builtin_amdgcn_mfma_f32_16x16x32_bf16(a0, x0, acc, 0, 0, 0);
      acc = __builtin_amdgcn_mfma_f32_16x16x32_bf16(a1, x1, acc, 0, 0, 0);
      acc = __builtin_amdgcn_mfma_f32_16x16x32_bf16(a2, x2, acc, 0, 0, 0);
      int rl = nt*16 + col;
      if (rl < 49) {
        int ij = ij0 + rl;
        // D: col = lane&15 (= ij), row = quad*4 + r (= d within m-tile) [m89]
#pragma unroll
        for (int r = 0; r < 4; ++r) {
          int d = d0 + wave*16 + quad*4 + r;
          int c = d >> 3, h = d & 7;
          float val = acc[r] + bb[r];
          if (ten == 2) {
            Vb[((size_t)((b*8 + h)*96 + c))*kKeyP + ij*4 + g] = __float2bfloat16(val);
          } else {
            __hip_bfloat16* dst = (ten == 0) ? Qb : Kb;
            dst[((size_t)((b*8 + h)*4 + g)*196 + ij)*96 + c] = __float2bfloat16(val);
          }
        }
      }
    }
  }

  // ---- fused setup tails ----
  if (ten == 1) {
    // Woh[h][d][c] = bf16(Wo[d][c*8+h]) -- per-head B-operand for outproj
    for (int idx = bid*512 + tid; idx < 73728; idx += 192*512) {
      int h = idx / 9216, rem = idx - h*9216;
      int d = rem / 96, c = rem - d*96;
      Woh[idx] = __float2bfloat16(Wo[(size_t)d*768 + c*8 + h]);
    }
  }
  if (ten == 2 && bid < 16) {
    // zero V key-pad [784,800) for bh = bid (interleaved indices stop at 783)
    for (int idx = tid; idx < 96*16; idx += 512) {
      int c = idx >> 4, kp = idx & 15;
      Vb[((size_t)(bid*96 + c))*kKeyP + kKey + kp] = __float2bfloat16(0.f);
    }
  }
  if (ten == 0 && bid == 0 && tid < 54) {
    int t = tid;
    int which = t / 27;
    int n = t % 27;
    float tv = (float)(n - 13) / 13.0f;
    const float* w1  = which ? cw1  : rw1;
    const float* b1  = which ? cb1  : rb1;
    const float* gam = which ? cgam : rgam;
    const float* bet = which ? cbet : rbet;
    const float* w2  = which ? cw2  : rw2;
    const float* b2  = which ? cb2  : rb2;
    float h[16];
    float mu = 0.f;
#pragma unroll
    for (int d = 0; d < 16; ++d) { h[d] = tv * w1[d] + b1[d]; mu += h[d]; }
    mu *= (1.0f/16.0f);
    float var = 0.f;
#pragma unroll
    for (int d = 0; d < 16; ++d) { float z = h[d] - mu; var += z*z; }
    var *= (1.0f/16.0f);
    float rstd = rsqrtf(var + 1e-5f);
#pragma unroll
    for (int d = 0; d < 16; ++d) {
      float z = (h[d] - mu) * rstd * gam[d] + bet[d];
      h[d] = z / (1.0f + expf(-z));   // silu
    }
    float* outp = (which ? fcol : frow) + n*32;
    for (int c = 0; c < 32; ++c) {
      float o = b2[c];
#pragma unroll
      for (int d = 0; d < 16; ++d) o += h[d] * w2[d*32 + c];
      outp[c] = o;
    }
  }
}

// ============================================================
// Kernel 2 (R20/R21-proven): fused content+bias+softmax+PV+outproj,
// in-place P, XCD-aware block swizzle (FETCH 3.9MB, k_attn ~50us).
// Restored verbatim after R22-R25 regressions (j-split, prefetch,
// LDS-cut/de-stage all measured neutral-to-worse).
// ============================================================
__global__ __launch_bounds__(512, 4)
void k_attn(const __hip_bfloat16* __restrict__ Qb, const __hip_bfloat16* __restrict__ Kb,
            const float* __restrict__ frow_g, const float* __restrict__ fcol_g,
            const float* __restrict__ gemb_g,
            const __hip_bfloat16* __restrict__ Vb,
            const __hip_bfloat16* __restrict__ Woh,
            const float* __restrict__ bo, float* __restrict__ out) {
  const int tid = threadIdx.x;
  const int bid = blockIdx.x;
  // ---- XCD-aware decode: bid&7 = XCD slot; 56 blocks/XCD = 2 bh x 28.
  const int xcd  = bid & 7;
  const int slot = bid >> 3;               // 0..55
  const int sub  = (slot >= 28);
  const int within = slot - sub*28;        // 0..27
  const int bh = xcd*2 + sub;
  const int qi = within >> 1;
  const int jhalf = within & 1;

  // ---- LDS ----
  __shared__ alignas(16) char poolA[19104];              // qs|tables -> vos
  __shared__ alignas(16) __hip_bfloat16 contl[kQR][kPS]; // E -> P in place
  __shared__ alignas(16) float ArrE[kQR][28];            // exp2(row bias dot)
  __shared__ alignas(16) float AclE[kQR][28];            // exp2(col bias dot)
  __shared__ alignas(16) float AgEall[4][kQR][4];        // exp2(grp bias), rotated per v
  __shared__ float T[4][kQR][14];                        // pass-B partials, all v
  __shared__ float DinvS[4][kQR];

  float (*qs)[96] = (float(*)[96])poolA;               // [28][96] fp32 (phases 1-2b)
  float* frowS = (float*)(poolA + 10752);              // 27*kTS fp32
  float* fcolS = (float*)(poolA + 10752 + 3888);       // 27*kTS fp32
  float* gembS = (float*)(poolA + 10752 + 2*3888);     // 4*kTS fp32
  __hip_bfloat16 (*vos)[104] = (__hip_bfloat16(*)[104])poolA;  // [32][104] (phase 4)

  const short* Qs = (const short*)Qb;
  const short* Ks = (const short*)Kb;

  // ---- phase 1: stage fp32 query copies + tables (pre-scaled to exp2 domain)
  for (int idx = tid; idx < kQR*96; idx += 512) {
    int q = idx / 96, c = idx - q*96;
    int g = q / 7, jq = q - g*7;
    qs[q][c] = __bfloat162float(
        Qb[((size_t)((bh*4 + g)*kSS + qi*14 + jhalf*7 + jq))*96 + c]);
  }
  for (int idx = tid; idx < 864; idx += 512) {
    int s = idx >> 5, c = idx & 31;
    frowS[s*kTS + c] = frow_g[idx] * kK2;
    fcolS[s*kTS + c] = fcol_g[idx] * kK2;
  }
  if (tid < 128) gembS[(tid >> 5)*kTS + (tid & 31)] = gemb_g[tid] * kK2;
  __syncthreads();

  // ---- phase 2a: MFMA content GEMM -> contl (E = exp2(content*kK2 - Cc), bf16)
  // plus: zero P pad cols [784,808) once (E never touches them; PV needs 0).
  for (int idx = tid; idx < kQR*24; idx += 512) {
    int r = idx / 24, c2 = idx - r*24;
    contl[r][784 + c2] = __float2bfloat16(0.f);
  }
  {
    const int lane = tid & 63;
    const int wave = tid >> 6;
    const int col  = lane & 15;
    const int quad = lane >> 4;

    bf16x8 afrag[2][3];
#pragma unroll
    for (int mt = 0; mt < 2; ++mt) {
      int m = mt*16 + col;
      int q = (m < kQR) ? m : 0;                 // pad rows: duplicate q0 (discarded)
      const short* qrow = Qs +
          ((size_t)((bh*4 + q/7)*kSS + qi*14 + jhalf*7 + q%7))*96;
#pragma unroll
      for (int ks = 0; ks < 3; ++ks)
        afrag[mt][ks] = *(const bf16x8*)(qrow + ks*32 + quad*8);
    }

    for (int nt = wave; nt < 49; nt += 8) {
      int kl = nt*16 + col;                      // key index g_key*196 + ij
      const short* krow = Ks + ((size_t)(bh*kKey + kl))*96;
      bf16x8 b0 = *(const bf16x8*)(krow + 0*32 + quad*8);
      bf16x8 b1 = *(const bf16x8*)(krow + 1*32 + quad*8);
      bf16x8 b2 = *(const bf16x8*)(krow + 2*32 + quad*8);
      f32x4 c0 = {0.f,0.f,0.f,0.f};
      f32x4 c1 = {0.f,0.f,0.f,0.f};
      c0 = __builtin_amdgcn_mfma_f32_16x16x32_bf16(afrag[0][0], b0, c0, 0, 0, 0);
      c0 = __builtin_amdgcn_mfma_f32_16x16x32_bf16(afrag[0][1], b1, c0, 0, 0, 0);
      c0 = __builtin_amdgcn_mfma_f32_16x16x32_bf16(afrag[0][2], b2, c0, 0, 0, 0);
      c1 = __builtin_amdgcn_mfma_f32_16x16x32_bf16(afrag[1][0], b0, c1, 0, 0, 0);
      c1 = __builtin_amdgcn_mfma_f32_16x16x32_bf16(afrag[1][1], b1, c1, 0, 0, 0);
      c1 = __builtin_amdgcn_mfma_f32_16x16x32_bf16(afrag[1][2], b2, c1, 0, 0, 0);
      int ijn = kl % 196, mk = kl / 196;         // interleaved store position
      // C/D layout: col = lane&15 (=kl), row = quad*4 + r (=q)  [m89]
#pragma unroll
      for (int r = 0; r < 4; ++r) {
        int q0 = quad*4 + r;                     // 0..15, all valid
        contl[q0][ijn*4 + mk] = __float2bfloat16(exp2f(c0[r]*kK2 - kCc));
        int q1 = 16 + quad*4 + r;                // 16..31, valid < 28
        if (q1 < kQR)
          contl[q1][ijn*4 + mk] = __float2bfloat16(exp2f(c1[r]*kK2 - kCc));
      }
    }
  }

  // ---- phase 2b: bias tables, EXP2-APPLIED (ArrE/AclE) + AgE pre-rotated all v
  for (int t = tid; t < kQR*58; t += 512) {
    int q = t / 58, s = t - q*58;
    float acc = 0.f;
    if (s < 27) {
#pragma unroll
      for (int c = 0; c < 32; ++c) acc += qs[q][c] * frowS[s*kTS + c];
      ArrE[q][s] = exp2f(acc);
    } else if (s < 54) {
      int n = s - 27;
#pragma unroll
      for (int c = 0; c < 32; ++c) acc += qs[q][32+c] * fcolS[n*kTS + c];
      AclE[q][n] = exp2f(acc);
    } else {
      int p = s - 54;
#pragma unroll
      for (int c = 0; c < 32; ++c) acc += qs[q][64+c] * gembS[p*kTS + c];
      float e = exp2f(acc);
      int gq = q / 7;
      // AgEall[v][q][m] with (m - gq + v)&3 == p  =>  m = (p + gq - v)&3
#pragma unroll
      for (int vv = 0; vv < 4; ++vv)
        AgEall[vv][q][(p + gq - vv + 8) & 3] = e;
    }
  }
  __syncthreads();

  const int actv = (tid < 392);
  // pass-B mapping: thread = (q, kk)
  const int qB  = actv ? (tid / 14) : 0;
  const int kkB = actv ? (tid % 14) : 0;
  const int jlB = jhalf*7 + (qB % 7);
  const int daB = kkB - qi;
  // pass-C mapping: thread = (half, ij)
  const int half = actv ? (tid / 196) : 0;
  const int ijC  = actv ? (tid % 196) : 0;
  const int kkC = ijC / 14;
  const int llC = ijC % 14;
  const int daC = kkC - qi;

  // ---- pass B, all 4 v fused: one E load feeds 4 accumulators.
  if (actv) {
    f32x4 ag0 = *(const f32x4*)(&AgEall[0][qB][0]);
    f32x4 ag1 = *(const f32x4*)(&AgEall[1][qB][0]);
    f32x4 ag2 = *(const f32x4*)(&AgEall[2][qB][0]);
    f32x4 ag3 = *(const f32x4*)(&AgEall[3][qB][0]);
    const float* Ar = &ArrE[qB][13];
    const float* Ac = &AclE[qB][13];
    float a0 = 0.f, a1 = 0.f, a2 = 0.f, a3 = 0.f;
#pragma unroll
    for (int ll = 0; ll < 14; ++ll) {
      const int db = ll - jlB;
      ushort4 u = *(const ushort4*)(&contl[qB][(kkB*14 + ll)*4]);
      float e0 = __uint_as_float((unsigned)u.x << 16);
      float e1 = __uint_as_float((unsigned)u.y << 16);
      float e2 = __uint_as_float((unsigned)u.z << 16);
      float e3 = __uint_as_float((unsigned)u.w << 16);
      a0 += Ac[ db] * (e0*ag0.x + e1*ag0.y + e2*ag0.z + e3*ag0.w);
      a1 += Ar[-db] * (e0*ag1.x + e1*ag1.y + e2*ag1.z + e3*ag1.w);
      a2 += Ac[-db] * (e0*ag2.x + e1*ag2.y + e2*ag2.z + e3*ag2.w);
      a3 += Ar[ db] * (e0*ag3.x + e1*ag3.y + e2*ag3.z + e3*ag3.w);
    }
    T[0][qB][kkB] = Ar[ daB] * a0;
    T[1][qB][kkB] = Ac[ daB] * a1;
    T[2][qB][kkB] = Ar[-daB] * a2;
    T[3][qB][kkB] = Ac[-daB] * a3;
  }
  __syncthreads();
  if (tid < 112) {
    int v = tid / 28, q = tid - v*28;
    float dsum = 0.f;
#pragma unroll
    for (int kk = 0; kk < 14; ++kk) dsum += T[v][q][kk];
    DinvS[v][q] = 1.0f / dsum;
  }
  __syncthreads();

  // ---- pass C, all 4 v fused, IN PLACE: preload this thread's 28 E words,
  // then overwrite the same cells with P rows [jq*4+v][ij*4+m].
  if (actv) {
    unsigned p32[kQR];
#pragma unroll
    for (int q = 0; q < kQR; ++q)
      p32[q] = *(const unsigned*)(&contl[q][ijC*4 + half*2]);
#pragma unroll
    for (int v = 0; v < 4; ++v) {
      const int s1a = (v==0) ? 1 : (v==2) ? -1 : 0;
      const int s1b = (v==1) ? -1 : (v==3) ? 1 : 0;
      const int s2a = (v==1) ? 1 : (v==3) ? -1 : 0;
      const int s2b = (v==0) ? 1 : (v==2) ? -1 : 0;
#pragma unroll
      for (int jq = 0; jq < 7; ++jq) {
        const int db = llC - (jhalf*7 + jq);
        const int ai = s1a*daC + s1b*db, ci = s2a*daC + s2b*db;
        float am0 = 0.f, am1 = 0.f;
#pragma unroll
        for (int gq = 0; gq < 4; ++gq) {
          const int q = gq*7 + jq;
          const float fq = ArrE[q][13 + ai] * AclE[q][13 + ci] * DinvS[v][q];
          unsigned u = p32[q];
          float e0 = __uint_as_float(u << 16);
          float e1 = __uint_as_float(u & 0xffff0000u);
          am0 += e0 * (AgEall[v][q][half*2]     * fq);
          am1 += e1 * (AgEall[v][q][half*2 + 1] * fq);
        }
        __hip_bfloat16* pp = &contl[jq*4 + v][ijC*4 + half*2];
        pp[0] = __float2bfloat16(am0);
        pp[1] = __float2bfloat16(am1);
      }
    }
  }
  __syncthreads();   // P complete in contl

  const int lane = tid & 63;
  const int wave = tid >> 6;
  const int col  = lane & 15;
  const int quad = lane >> 4;
  const int b_ = bh >> 3, h_ = bh & 7;

  // ---- phase 3: PV. vo[28][96] = P[28x800] . V[800x96] (k = ij*4+g order).
  {
    const short* Bp = (const short*)Vb + ((size_t)bh*96)*kKeyP + quad*8;
#pragma unroll
    for (int tk = 0; tk < 2; ++tk) {
      int t = wave + tk*8;
      if (t < 12) {
        int mt = t / 6, nt = t - mt*6;
        int crow = nt*16 + col;
        int prow = mt*16 + col; if (prow >= kQR) prow = 0;  // dup row0 (discarded)
        const short* ap = (const short*)(&contl[prow][0]) + quad*8;
        const short* bp = Bp + (size_t)crow*kKeyP;
        f32x4 acc = {0.f,0.f,0.f,0.f};
        for (int ks = 0; ks < 25; ++ks) {
          bf16x8 a = *(const bf16x8*)(ap + ks*32);
          bf16x8 b = *(const bf16x8*)(bp + ks*32);
          acc = __builtin_amdgcn_mfma_f32_16x16x32_bf16(a, b, acc, 0, 0, 0);
        }
        // D: col = lane&15 (= c in n-tile), row = quad*4 + r (= P row in m-tile)
#pragma unroll
        for (int r = 0; r < 4; ++r)
          vos[mt*16 + quad*4 + r][crow] = __float2bfloat16(acc[r]);
      }
    }
  }
  __syncthreads();

  // ---- phase 4: outproj. out += vos . Woh[h]^T (+ bo if h==0). 12 tasks.
  {
    const short* wb = (const short*)Woh + (size_t)h_*9216;
#pragma unroll
    for (int tk = 0; tk < 2; ++tk) {
      int t = wave + tk*8;
      if (t < 12) {
        int mt = t / 6, dt = t - mt*6;
        f32x4 acc = {0.f,0.f,0.f,0.f};
#pragma unroll
        for (int ks = 0; ks < 3; ++ks) {
          bf16x8 a = *(const bf16x8*)(&vos[mt*16 + col][ks*32 + quad*8]);
          bf16x8 b = *(const bf16x8*)(wb + (size_t)(dt*16 + col)*96 + ks*32 + quad*8);
          acc = __builtin_amdgcn_mfma_f32_16x16x32_bf16(a, b, acc, 0, 0, 0);
        }
        const int d = dt*16 + col;              // D col = lane&15 = d-in-tile
        const float bias = (h_ == 0) ? bo[d] : 0.f;
#pragma unroll
        for (int r = 0; r < 4; ++r) {
          int rr = mt*16 + quad*4 + r;          // P/vo row = jq*4 + v
          if (rr < kQR) {
            int jq = rr >> 2, vv = rr & 3;
            int ijq = qi*14 + jhalf*7 + jq;
            atomicAdd(&out[((size_t)(b_*96 + d)*4 + vv)*kSS + ijq], acc[r] + bias);
          }
        }
      }
    }
  }
}

// ============================================================
extern "C" void kernel_launch(void* const* d_in, const int* in_sizes, int n_in,
                              void* d_out, int out_size, void* d_ws, size_t ws_size,
                              hipStream_t stream) {
  const float* x    = (const float*)d_in[0];
  const float* Wq   = (const float*)d_in[1];
  const float* bq   = (const float*)d_in[2];
  const float* Wk   = (const float*)d_in[3];
  const float* bk   = (const float*)d_in[4];
  const float* Wv   = (const float*)d_in[5];
  const float* bv   = (const float*)d_in[6];
  const float* Wo   = (const float*)d_in[7];
  const float* bo   = (const float*)d_in[8];
  const float* rw1  = (const float*)d_in[9];
  const float* rb1  = (const float*)d_in[10];
  const float* rgam = (const float*)d_in[11];
  const float* rbet = (const float*)d_in[12];
  const float* rw2  = (const float*)d_in[13];
  const float* rb2  = (const float*)d_in[14];
  const float* cw1  = (const float*)d_in[15];
  const float* cb1  = (const float*)d_in[16];
  const float* cgam = (const float*)d_in[17];
  const float* cbet = (const float*)d_in[18];
  const float* cw2  = (const float*)d_in[19];
  const float* cb2  = (const float*)d_in[20];
  const float* gemb = (const float*)d_in[21];
  // d_in[22..24] = row_rel, col_rel, g_idx: reconstructed analytically.

  float* ws = (float*)d_ws;
  __hip_bfloat16* Qb = (__hip_bfloat16*)(ws + OFF_Qb);
  __hip_bfloat16* Kb = (__hip_bfloat16*)(ws + OFF_Kb);
  __hip_bfloat16* Vb = (__hip_bfloat16*)(ws + OFF_V);
  float* Frow = ws + OFF_FR;
  float* Fcol = ws + OFF_FC;
  __hip_bfloat16* Woh = (__hip_bfloat16*)(ws + OFF_WOH);
  float* out  = (float*)d_out;

  k_qkv<<<dim3(192, 3), 512, 0, stream>>>(x, Wq, bq, Wk, bk, Wv, bv, Qb, Kb, Vb,
                                          rw1, rb1, rgam, rbet, rw2, rb2,
                                          cw1, cb1, cgam, cbet, cw2, cb2,
                                          Frow, Fcol, Wo, Woh, out);
  k_attn<<<448, 512, 0, stream>>>(Qb, Kb, Frow, Fcol, gemb, Vb, Woh, bo, out);
}